// Round 7
// baseline (135.945 us; speedup 1.0000x reference)
//
#include <hip/hip_runtime.h>
#include <hip/hip_bf16.h>

// Attention_82841329205539: B=2, N=2048, C=768, H=12, D=64, window=129
// Inputs fp32 (dict order), OUTPUT fp32 [B,N,C].
// r6:1485 r7:809 r8:444 r10:270 r11:275 r12:253 r13:166.6 r14:159.9 r15:131.4
// r16:132.4 r17:130.7 r18:120.4 r19:FAIL(absmax) r20:FAIL(tripwire nondet).
// r20 post-mortem: shared-ring cross-wave handoff has an intermittent race I
// cannot prove away. This round removes the hazard CLASS: SELF-STAGED rings.
// Each wave stages its own A-half/B-half into its own LDS region (depth-2,
// BK=32); ordering is purely per-wave (own vmcnt(8) wait at step top, own
// lgkmcnt(0)+sched_barrier before the slot overwrite). ZERO barriers in the
// K-loop, zero cross-wave deps -> deterministic by construction. Staging
// bytes 2x (L2 absorbs). proj: register-direct epilogue (no LDS epilogue,
// no barriers at all; LDS 40KB -> 4 blk/CU). swin/cvt3 frozen.
#define Bsz   2
#define Nseq  2048
#define Cdim  768
#define E3    2304
#define Hh    12
#define Dd    64
#define HALF  64
#define SCALEF 0.125f

typedef __attribute__((ext_vector_type(8))) short short8;
typedef __attribute__((ext_vector_type(4))) float f32x4;

#define FENCE_LGKM() do {                                                  \
    asm volatile("s_waitcnt lgkmcnt(0)" ::: "memory");                     \
    __builtin_amdgcn_sched_barrier(0);                                     \
} while (0)

__device__ __forceinline__ unsigned short f2bf(float f) {
    unsigned int u = __float_as_uint(f);
    u = (u + 0x7FFFu + ((u >> 16) & 1u)) >> 16;
    return (unsigned short)u;
}
__device__ __forceinline__ unsigned int pk2(float a, float b) {
    __hip_bfloat162 h = __float22bfloat162_rn(make_float2(a, b));
    union { __hip_bfloat162 h2; unsigned int u; } cv; cv.h2 = h; return cv.u;
}
__device__ __forceinline__ uint4 cvt8(const float4& lo, const float4& hi) {
    return make_uint4(pk2(lo.x, lo.y), pk2(lo.z, lo.w),
                      pk2(hi.x, hi.y), pk2(hi.z, hi.w));
}

// global -> LDS direct DMA, 16B per lane. LDS dest wave-uniform base +
// lane*16 (linear); global src per-lane.
__device__ __forceinline__ void gl_lds16(const unsigned short* g, unsigned short* l) {
    __builtin_amdgcn_global_load_lds(
        (__attribute__((address_space(1))) void*)(g),
        (__attribute__((address_space(3))) void*)(l), 16, 0, 0);
}

// ---------------------------------------------------------------------------
// Kernel 0: fp32 -> bf16 pre-convert (x, w_qkv, w_proj).
// ---------------------------------------------------------------------------
__global__ __launch_bounds__(256) void cvt3(
    const float* __restrict__ x, const float* __restrict__ wq,
    const float* __restrict__ wp, unsigned short* __restrict__ xb,
    unsigned short* __restrict__ wqb, unsigned short* __restrict__ wpb)
{
    const int gid = blockIdx.x * 256 + threadIdx.x;   // 0..688127
    const float* src; unsigned short* dst; int off;
    if (gid < 393216)      { src = x;  dst = xb;  off = gid; }
    else if (gid < 614400) { src = wq; dst = wqb; off = gid - 393216; }
    else                   { src = wp; dst = wpb; off = gid - 614400; }
    const float4 lo = *(const float4*)&src[(size_t)off * 8];
    const float4 hi = *(const float4*)&src[(size_t)off * 8 + 4];
    *(uint4*)&dst[(size_t)off * 8] = cvt8(lo, hi);
}

// ---------------------------------------------------------------------------
// Kernel 1: QKV GEMM, pure bf16. 128Mx128N, BK=32, 24 K-steps. SELF-STAGED
// depth-2 ring: wave w stages A rows wm*64..+63 and B rows wn*64..+63 into
// its own 16KB LDS region (2 slots x 8KB: A 4KB + B 4KB). Per step: own
// vmcnt(8) wait -> 8 ds_read_b128 + 16 MFMA -> lgkmcnt(0) fence -> 8 DMAs
// for step k+2. No barriers in the loop. LDS 64KB. grid 576 (18x32),
// bijective XCD swizzle.
// ---------------------------------------------------------------------------
__global__ __launch_bounds__(256) void qkv_mfma(
    const unsigned short* __restrict__ xb, const unsigned short* __restrict__ wqb,
    unsigned short* __restrict__ qkvb)
{
    __shared__ __align__(16) unsigned short smem[32768];   // 4 waves x 2 x 4096

    const int t  = threadIdx.x;
    const int id = blockIdx.y * 18 + blockIdx.x;
    const int p8 = id & 7, j8 = id >> 3;           // 72 tiles per XCD
    const int wg = p8 * 72 + j8;
    const int by = wg / 18, bx = wg % 18;
    const int row0 = by * 128, col0 = bx * 128;

    const int lane = t & 63, wave = t >> 6;
    const int wm = wave >> 1, wn = wave & 1;
    const int ln = lane & 15, quad = lane >> 4;

    // self-staging sources: wave's own A-half / B-half rows
    const unsigned short* aSrc = &xb [(size_t)(row0 + wm*64 + (lane>>2)) * Cdim
                                      + (lane&3)*8];
    const unsigned short* bSrc = &wqb[(size_t)(col0 + wn*64 + (lane>>2)) * Cdim
                                      + (lane&3)*8];
    unsigned short* wl = &smem[wave * 8192];       // wave-private region

    f32x4 acc[4][4] = {};

    auto STAGE = [&](int tt) {                     // 8 DMAs, own region only
        unsigned short* d = wl + (tt & 1) * 4096;
        const int ko = tt * 32;
#pragma unroll
        for (int j = 0; j < 4; ++j) {
            gl_lds16(aSrc + ko + (size_t)(16*j) * Cdim, d + j*512);
            gl_lds16(bSrc + ko + (size_t)(16*j) * Cdim, d + 2048 + j*512);
        }
    };
    auto COMP = [&](int s) {                       // reads own region only
        const unsigned short* ba = wl + s * 4096;
        short8 af[4], bf[4];
#pragma unroll
        for (int mi = 0; mi < 4; ++mi)
            af[mi] = *(const short8*)&ba[(mi*16 + ln)*32 + quad*8];
#pragma unroll
        for (int ni = 0; ni < 4; ++ni)
            bf[ni] = *(const short8*)&ba[2048 + (ni*16 + ln)*32 + quad*8];
#pragma unroll
        for (int mi = 0; mi < 4; ++mi)
#pragma unroll
            for (int ni = 0; ni < 4; ++ni)
                acc[mi][ni] = __builtin_amdgcn_mfma_f32_16x16x32_bf16(
                    af[mi], bf[ni], acc[mi][ni], 0, 0, 0);
    };

    STAGE(0); STAGE(1);                            // 16 own DMAs in flight
#pragma unroll
    for (int k = 0; k < 24; ++k) {
        if (k < 23) { asm volatile("s_waitcnt vmcnt(8)" ::: "memory"); }
        else        { asm volatile("s_waitcnt vmcnt(0)" ::: "memory"); }
        __builtin_amdgcn_sched_barrier(0);
        COMP(k & 1);
        FENCE_LGKM();                              // own reads retired
        if (k + 2 < 24) STAGE(k + 2);              // overwrite own slot k&1
    }

    // epilogue: two 64-col passes via LDS (waves with wn==p own pass p cols)
    __syncthreads();                               // full drain + barrier
    unsigned short (*Cs)[72] = (unsigned short(*)[72])smem;   // 128x72
    const int rA = t >> 3, c8 = t & 7;
#pragma unroll
    for (int p = 0; p < 2; ++p) {
        __syncthreads();
        if (wn == p) {
#pragma unroll
            for (int mi = 0; mi < 4; ++mi)
#pragma unroll
                for (int ni = 0; ni < 4; ++ni)
#pragma unroll
                    for (int reg = 0; reg < 4; ++reg)
                        Cs[wm*64 + mi*16 + quad*4 + reg][ni*16 + ln] =
                            f2bf(acc[mi][ni][reg]);
        }
        __syncthreads();
#pragma unroll
        for (int j = 0; j < 4; ++j)
            *(uint4*)&qkvb[(size_t)(row0 + rA + j*32) * E3 + col0 + p*64 + c8*8] =
                *(const uint4*)&Cs[rA + j*32][c8*8];
    }
}

// ---------------------------------------------------------------------------
// Kernel 3: output projection + bias -> fp32. 64x64 tile, BK=32, 24 steps.
// SELF-STAGED depth-2 ring: wave w stages its A rows w*16..+15 (1 DMA) and
// ALL 64 B rows (4 DMAs) into its own 10KB region (2 x 5KB). Own vmcnt(5)
// wait per step; no barriers anywhere (register-direct epilogue, bias
// preloaded). LDS 40KB -> 4 blk/CU. grid (12,64) = 768 blocks.
// ---------------------------------------------------------------------------
__global__ __launch_bounds__(256) void proj_mfma(
    const unsigned short* __restrict__ Ab, const unsigned short* __restrict__ wpb,
    const float* __restrict__ bias, float* __restrict__ out)
{
    __shared__ __align__(16) unsigned short smem[20480];   // 4 waves x 2 x 2560

    const int t  = threadIdx.x;
    const int id = blockIdx.y * 12 + blockIdx.x;
    const int p8 = id & 7, j2 = id >> 3;
    const int bx = j2 % 12;
    const int by = p8 * 8 + j2 / 12;
    const int row0 = by * 64, col0 = bx * 64;

    const int lane = t & 63, wave = t >> 6;
    const int ln = lane & 15, quad = lane >> 4;

    const unsigned short* aSrc = &Ab [(size_t)(row0 + wave*16 + (lane>>2)) * Cdim
                                      + (lane&3)*8];
    const unsigned short* bSrc = &wpb[(size_t)(col0 + (lane>>2)) * Cdim
                                      + (lane&3)*8];
    unsigned short* wl = &smem[wave * 5120];

    float bv[4];
#pragma unroll
    for (int ni = 0; ni < 4; ++ni)
        bv[ni] = bias[col0 + ni*16 + ln];

    f32x4 acc[4] = {};

    auto STAGE = [&](int tt) {                     // 5 DMAs, own region
        unsigned short* d = wl + (tt & 1) * 2560;
        const int ko = tt * 32;
        gl_lds16(aSrc + ko, d);                    // own 16 A rows
#pragma unroll
        for (int j = 0; j < 4; ++j)                // all 64 B rows
            gl_lds16(bSrc + ko + (size_t)(16*j) * Cdim, d + 512 + j*512);
    };
    auto COMP = [&](int s) {
        const unsigned short* ba = wl + s * 2560;
        short8 af = *(const short8*)&ba[ln*32 + quad*8];
#pragma unroll
        for (int ni = 0; ni < 4; ++ni) {
            short8 bf = *(const short8*)&ba[512 + (ni*16 + ln)*32 + quad*8];
            acc[ni] = __builtin_amdgcn_mfma_f32_16x16x32_bf16(af, bf, acc[ni], 0, 0, 0);
        }
    };

    STAGE(0); STAGE(1);                            // 10 own DMAs in flight
#pragma unroll
    for (int k = 0; k < 24; ++k) {
        if (k < 23) { asm volatile("s_waitcnt vmcnt(5)" ::: "memory"); }
        else        { asm volatile("s_waitcnt vmcnt(0)" ::: "memory"); }
        __builtin_amdgcn_sched_barrier(0);
        COMP(k & 1);
        FENCE_LGKM();
        if (k + 2 < 24) STAGE(k + 2);
    }

    // epilogue: register-direct stores, fused bias (no LDS, no barriers)
#pragma unroll
    for (int ni = 0; ni < 4; ++ni)
#pragma unroll
        for (int reg = 0; reg < 4; ++reg)
            out[(size_t)(row0 + wave*16 + quad*4 + reg) * Cdim
                + col0 + ni*16 + ln] = acc[ni][reg] + bv[ni];
}

// ---------------------------------------------------------------------------
// Kernel 2: sliding-window attention, TQ=64 per block, 4 waves (frozen from
// r17). Wave w owns 16 query rows end-to-end; K[192][64] DMA-staged
// (clamped rows, masked post-MFMA); Vt granule-swizzled overlay; register
// softmax. LDS 51.4KB; grid 768, bijective XCD swizzle.
// ---------------------------------------------------------------------------
#define TQ2  64
#define VSTn 200
#define PSTn 200

__global__ __launch_bounds__(256) void swin_attn(
    const unsigned short* __restrict__ qkvb, unsigned short* __restrict__ ab)
{
    __shared__ __align__(16) unsigned short SH[64 * VSTn];   // 25600B K/Vt overlay
    __shared__ __align__(16) unsigned short Pl[TQ2][PSTn];   // 25600B
    __shared__ float psum[TQ2];                              //   256B

    const int t  = threadIdx.x;
    const int id = blockIdx.y * 32 + blockIdx.x;   // 768 blocks
    const int p8 = id & 7, j8 = id >> 3;           // 96 per XCD
    const int bh = j8 >> 2;
    const int i0 = (p8 * 4 + (j8 & 3)) * TQ2;
    const int b  = bh / Hh, h = bh % Hh;
    const int hoff = h * Dd;

    const int lane = t & 63, wave = t >> 6;
    const int ln = lane & 15, quad = lane >> 4;
    const int lr  = lane >> 3;
    const int scw = ((lane ^ lr) & 7) * 8;   // pre-swizzled src col (shorts)
    const int xsw = (ln & 7) << 3;           // read-side XOR
    const int rV  = t >> 3, c8 = t & 7;

    // ---- Q fragments (wave's 16 query rows)
    short8 qf[2];
#pragma unroll
    for (int kc = 0; kc < 2; ++kc)
        qf[kc] = *(const short8*)&qkvb[(size_t)(b * Nseq + i0 + wave*16 + ln) * E3
                                       + hoff + kc*32 + quad*8];

    // ---- V rows -> regs (clamped; P==0 exactly on masked/OOB keys)
    uint4 vreg[6];
#pragma unroll
    for (int j = 0; j < 6; ++j) {
        int g = i0 - HALF + rV + j*32;
        g = min(max(g, 0), Nseq - 1);
        vreg[j] = *(const uint4*)&qkvb[(size_t)(b * Nseq + g) * E3 + 2*Cdim + hoff + c8*8];
    }

    // ---- K -> LDS via DMA (24 x 8-row groups; clamped rows)
#pragma unroll
    for (int j = 0; j < 6; ++j) {
        const int base = (j*4 + wave) * 8;
        int g = i0 - HALF + base + lr;
        g = min(max(g, 0), Nseq - 1);
        gl_lds16(&qkvb[(size_t)(b * Nseq + g) * E3 + Cdim + hoff + scw],
                 &SH[base * 64]);
    }
    __syncthreads();

    // ---- S phase: wave's queries need key tiles [wave, wave+8]
    f32x4 sacc[9] = {};
#pragma unroll
    for (int kc = 0; kc < 2; ++kc)
#pragma unroll
        for (int tt = 0; tt < 9; ++tt) {
            short8 kf = *(const short8*)&SH[((wave + tt)*16 + ln)*64
                                            + ((kc*32 + quad*8) ^ xsw)];
            sacc[tt] = __builtin_amdgcn_mfma_f32_16x16x32_bf16(qf[kc], kf, sacc[tt], 0, 0, 0);
        }

    // ---- mask + row max, all register-local (wave owns full rows)
    float pm[4] = {-1e30f, -1e30f, -1e30f, -1e30f};
#pragma unroll
    for (int tt = 0; tt < 9; ++tt) {
        const int r = (wave + tt)*16 + ln;
        const int g = i0 - HALF + r;
#pragma unroll
        for (int reg = 0; reg < 4; ++reg) {
            const int q = wave*16 + quad*4 + reg;
            const bool valid = (r >= q) && (r <= q + 2*HALF) && (g >= 0) && (g < Nseq);
            const float s = valid ? sacc[tt][reg] * SCALEF : -1e30f;
            sacc[tt][reg] = s;
            pm[reg] = fmaxf(pm[reg], s);
        }
    }
#pragma unroll
    for (int reg = 0; reg < 4; ++reg) {
        pm[reg] = fmaxf(pm[reg], __shfl_xor(pm[reg], 1));
        pm[reg] = fmaxf(pm[reg], __shfl_xor(pm[reg], 2));
        pm[reg] = fmaxf(pm[reg], __shfl_xor(pm[reg], 4));
        pm[reg] = fmaxf(pm[reg], __shfl_xor(pm[reg], 8));
    }
    float ps[4] = {};
#pragma unroll
    for (int reg = 0; reg < 4; ++reg)
#pragma unroll
        for (int tt = 0; tt < 9; ++tt) {
            const float pv = (sacc[tt][reg] > -1e29f) ? __expf(sacc[tt][reg] - pm[reg]) : 0.f;
            sacc[tt][reg] = pv;
            ps[reg] += pv;
        }
#pragma unroll
    for (int reg = 0; reg < 4; ++reg) {
        ps[reg] += __shfl_xor(ps[reg], 1);
        ps[reg] += __shfl_xor(ps[reg], 2);
        ps[reg] += __shfl_xor(ps[reg], 4);
        ps[reg] += __shfl_xor(ps[reg], 8);
    }

    // ---- P stores, boundary-tile zero, psum store.
#pragma unroll
    for (int tt = 0; tt < 9; ++tt)
#pragma unroll
        for (int reg = 0; reg < 4; ++reg)
            Pl[wave*16 + quad*4 + reg][(wave + tt)*16 + ln] = f2bf(sacc[tt][reg]);
    {
        const int tz = (wave & 1) ? (wave - 1) : (wave + 9);
        *(uint2*)&Pl[wave*16 + ln][tz*16 + quad*4] = make_uint2(0u, 0u);
    }
    if (ln == 0)
#pragma unroll
        for (int reg = 0; reg < 4; ++reg)
            psum[wave*16 + quad*4 + reg] = ps[reg];
    __syncthreads();   // all waves' K reads complete -> Vt overlay safe

    // ---- Vt transpose stores, granule-swizzled (2-way banks = free)
#pragma unroll
    for (int j = 0; j < 6; ++j) {
        const int r = rV + j*32;
        const int gr = ((r >> 3) ^ c8)*8 + (r & 7);
        union { unsigned short us[8]; uint4 u; } pk; pk.u = vreg[j];
#pragma unroll
        for (int d8 = 0; d8 < 8; ++d8)
            SH[(c8*8 + d8)*VSTn + gr] = pk.us[d8];
    }
    __syncthreads();

    // ---- PV: wave's own 16 queries (cols), all 64 dims, 5 kc blocks
    const int kc0 = wave >> 1;
    f32x4 oacc[4] = {};
#pragma unroll
    for (int c = 0; c < 5; ++c) {
        const int kc = kc0 + c;
        short8 pf = *(const short8*)&Pl[wave*16 + ln][kc*32 + quad*8];
#pragma unroll
        for (int m = 0; m < 4; ++m) {
            const int d = m*16 + ln;
            short8 vf = *(const short8*)&SH[d * VSTn
                                            + (((kc*4 + quad) ^ (d >> 3)) << 3)];
            oacc[m] = __builtin_amdgcn_mfma_f32_16x16x32_bf16(vf, pf, oacc[m], 0, 0, 0);
        }
    }

    const int q = wave*16 + ln;
    const float inv = 1.f / psum[q];
    unsigned short* orow = &ab[(size_t)(b * Nseq + i0 + q) * Cdim + hoff];
#pragma unroll
    for (int m = 0; m < 4; ++m) {
        const int d0 = m*16 + quad*4;
        union { unsigned short us[4]; uint2 u2; } pk;
#pragma unroll
        for (int reg = 0; reg < 4; ++reg)
            pk.us[reg] = f2bf(oacc[m][reg] * inv);
        *(uint2*)&orow[d0] = pk.u2;
    }
}

// ---------------------------------------------------------------------------
extern "C" void kernel_launch(void* const* d_in, const int* in_sizes, int n_in,
                              void* d_out, int out_size, void* d_ws, size_t ws_size,
                              hipStream_t stream)
{
    const float* x      = (const float*)d_in[0];
    const float* w_qkv  = (const float*)d_in[1];
    const float* w_proj = (const float*)d_in[2];
    const float* b_proj = (const float*)d_in[3];
    float* out = (float*)d_out;

    unsigned short* qkvb = (unsigned short*)d_ws;   // 9,437,184 shorts
    unsigned short* ab   = qkvb + 9437184;          // 3,145,728 shorts
    unsigned short* xb   = ab   + 3145728;          // 3,145,728 shorts
    unsigned short* wqb  = xb   + 3145728;          // 1,769,472 shorts
    unsigned short* wpb  = wqb  + 1769472;          //   589,824 shorts (36.2MB total)

    cvt3<<<dim3(2688), 256, 0, stream>>>(x, w_qkv, w_proj, xb, wqb, wpb);
    qkv_mfma<<<dim3(18, 32), 256, 0, stream>>>(xb, wqb, qkvb);
    swin_attn<<<dim3(32, Bsz * Hh), 256, 0, stream>>>(qkvb, ab);
    proj_mfma<<<dim3(12, 64), 256, 0, stream>>>(ab, wpb, b_proj, out);
}

// Round 8
// 119.669 us; speedup vs baseline: 1.1360x; 1.1360x over previous
//
#include <hip/hip_runtime.h>
#include <hip/hip_bf16.h>

// Attention_82841329205539: B=2, N=2048, C=768, H=12, D=64, window=129
// Inputs fp32 (dict order), OUTPUT fp32 [B,N,C].
// r6:1485 r7:809 r8:444 r10:270 r11:275 r12:253 r13:166.6 r14:159.9 r15:131.4
// r16:132.4 r17:130.7 r18:120.4 r19:FAIL r20:FAIL r21:135.9.
// Counted-vmcnt arc verdict: shared ring raced twice (m152), private ring is
// correct but pays 2x staging (-15.5us). At 12 K-steps the residual drain the
// deep pipeline recovers is smaller than its costs. This round: REVERT to
// r18's verified T3 double-buffer + __syncthreads structure (120.4us), with
// one r21-verified improvement kept: proj register-direct epilogue (no LDS
// round-trip, -4 barriers). swin/cvt3 frozen at r17/r14.
#define Bsz   2
#define Nseq  2048
#define Cdim  768
#define E3    2304
#define Hh    12
#define Dd    64
#define HALF  64
#define SCALEF 0.125f

typedef __attribute__((ext_vector_type(8))) short short8;
typedef __attribute__((ext_vector_type(4))) float f32x4;

__device__ __forceinline__ unsigned short f2bf(float f) {
    unsigned int u = __float_as_uint(f);
    u = (u + 0x7FFFu + ((u >> 16) & 1u)) >> 16;
    return (unsigned short)u;
}
__device__ __forceinline__ unsigned int pk2(float a, float b) {
    __hip_bfloat162 h = __float22bfloat162_rn(make_float2(a, b));
    union { __hip_bfloat162 h2; unsigned int u; } cv; cv.h2 = h; return cv.u;
}
__device__ __forceinline__ uint4 cvt8(const float4& lo, const float4& hi) {
    return make_uint4(pk2(lo.x, lo.y), pk2(lo.z, lo.w),
                      pk2(hi.x, hi.y), pk2(hi.z, hi.w));
}

// global -> LDS direct DMA, 16B per lane. LDS dest wave-uniform base +
// lane*16 (linear); global src per-lane (carries the swizzle).
__device__ __forceinline__ void gl_lds16(const unsigned short* g, unsigned short* l) {
    __builtin_amdgcn_global_load_lds(
        (__attribute__((address_space(1))) void*)(g),
        (__attribute__((address_space(3))) void*)(l), 16, 0, 0);
}

// ---------------------------------------------------------------------------
// Kernel 0: fp32 -> bf16 pre-convert (x, w_qkv, w_proj).
// ---------------------------------------------------------------------------
__global__ __launch_bounds__(256) void cvt3(
    const float* __restrict__ x, const float* __restrict__ wq,
    const float* __restrict__ wp, unsigned short* __restrict__ xb,
    unsigned short* __restrict__ wqb, unsigned short* __restrict__ wpb)
{
    const int gid = blockIdx.x * 256 + threadIdx.x;   // 0..688127
    const float* src; unsigned short* dst; int off;
    if (gid < 393216)      { src = x;  dst = xb;  off = gid; }
    else if (gid < 614400) { src = wq; dst = wqb; off = gid - 393216; }
    else                   { src = wp; dst = wpb; off = gid - 614400; }
    const float4 lo = *(const float4*)&src[(size_t)off * 8];
    const float4 hi = *(const float4*)&src[(size_t)off * 8 + 4];
    *(uint4*)&dst[(size_t)off * 8] = cvt8(lo, hi);
}

// ---------------------------------------------------------------------------
// Kernel 1: QKV GEMM, pure bf16. 128Mx128N, BK=64, DOUBLE-BUFFERED
// global_load_lds staging (T3 2-phase): issue next-tile DMA, then ds_read+
// MFMA current tile, then one __syncthreads (vmcnt(0) drain lands after
// MFMA). LDS 64KB (2 x [128][64]A + [128][64]B swizzled). grid 576 (18x32),
// bijective XCD swizzle. (r18-verified structure.)
// ---------------------------------------------------------------------------
__global__ __launch_bounds__(256) void qkv_mfma(
    const unsigned short* __restrict__ xb, const unsigned short* __restrict__ wqb,
    unsigned short* __restrict__ qkvb)
{
    __shared__ __align__(16) unsigned short smem[32768];   // 64 KB, 2 buffers

    const int t  = threadIdx.x;
    const int id = blockIdx.y * 18 + blockIdx.x;
    const int p8 = id & 7, j8 = id >> 3;           // 72 tiles per XCD
    const int wg = p8 * 72 + j8;
    const int by = wg / 18, bx = wg % 18;
    const int row0 = by * 128, col0 = bx * 128;

    const int lane = t & 63, wave = t >> 6;
    const int wm = wave >> 1, wn = wave & 1;
    const int ln = lane & 15, quad = lane >> 4;
    const int lr  = lane >> 3;
    const int sc  = ((lane ^ lr) & 7) * 8;         // pre-swizzled src col (shorts)
    const int xsw = (ln & 7) << 3;                 // read-side XOR (shorts)

    const unsigned short* Ag = &xb [(size_t)(row0 + wave*32 + lr) * Cdim + sc];
    const unsigned short* Bg = &wqb[(size_t)(col0 + wave*32 + lr) * Cdim + sc];

    f32x4 acc[4][4] = {};

    // prologue: stage tile 0 into buffer 0
#pragma unroll
    for (int j = 0; j < 4; ++j) {
        gl_lds16(Ag + (size_t)(j*8) * Cdim, &smem[(wave*4 + j) * 512]);
        gl_lds16(Bg + (size_t)(j*8) * Cdim, &smem[8192 + (wave*4 + j) * 512]);
    }
    __syncthreads();   // vmcnt(0): buffer 0 ready

    int cur = 0;
    for (int k0 = 0; k0 < Cdim; k0 += 64) {
        unsigned short* bc = smem + cur * 16384;
        if (k0 + 64 < Cdim) {           // prefetch next tile into other buffer
            unsigned short* bn = smem + (cur ^ 1) * 16384;
            const int kn = k0 + 64;
#pragma unroll
            for (int j = 0; j < 4; ++j) {
                gl_lds16(Ag + (size_t)(j*8) * Cdim + kn, &bn[(wave*4 + j) * 512]);
                gl_lds16(Bg + (size_t)(j*8) * Cdim + kn, &bn[8192 + (wave*4 + j) * 512]);
            }
        }
#pragma unroll
        for (int kk = 0; kk < 2; ++kk) {
            short8 af[4], bf[4];
#pragma unroll
            for (int mi = 0; mi < 4; ++mi)
                af[mi] = *(const short8*)&bc[(wm*64 + mi*16 + ln)*64
                                             + ((kk*32 + quad*8) ^ xsw)];
#pragma unroll
            for (int ni = 0; ni < 4; ++ni)
                bf[ni] = *(const short8*)&bc[8192 + (wn*64 + ni*16 + ln)*64
                                             + ((kk*32 + quad*8) ^ xsw)];
#pragma unroll
            for (int mi = 0; mi < 4; ++mi)
#pragma unroll
                for (int ni = 0; ni < 4; ++ni)
                    acc[mi][ni] = __builtin_amdgcn_mfma_f32_16x16x32_bf16(
                        af[mi], bf[ni], acc[mi][ni], 0, 0, 0);
        }
        __syncthreads();   // drains prefetch (after MFMA) + read-before-write
        cur ^= 1;
    }

    // epilogue: two 64-col passes via LDS (waves with wn==p own pass p cols)
    unsigned short (*Cs)[72] = (unsigned short(*)[72])smem;   // 128x72 = 18432 B
    const int rA = t >> 3, c8 = t & 7;
#pragma unroll
    for (int p = 0; p < 2; ++p) {
        __syncthreads();
        if (wn == p) {
#pragma unroll
            for (int mi = 0; mi < 4; ++mi)
#pragma unroll
                for (int ni = 0; ni < 4; ++ni)
#pragma unroll
                    for (int reg = 0; reg < 4; ++reg)
                        Cs[wm*64 + mi*16 + quad*4 + reg][ni*16 + ln] =
                            f2bf(acc[mi][ni][reg]);
        }
        __syncthreads();
#pragma unroll
        for (int j = 0; j < 4; ++j)
            *(uint4*)&qkvb[(size_t)(row0 + rA + j*32) * E3 + col0 + p*64 + c8*8] =
                *(const uint4*)&Cs[rA + j*32][c8*8];
    }
}

// ---------------------------------------------------------------------------
// Kernel 3: output projection + bias -> fp32. 64x64 tile, BK=64,
// double-buffered (T3 2-phase), LDS 32KB, register-direct epilogue
// (r21-verified: no LDS round-trip, no epilogue barriers). grid (12,64).
// ---------------------------------------------------------------------------
__global__ __launch_bounds__(256) void proj_mfma(
    const unsigned short* __restrict__ Ab, const unsigned short* __restrict__ wpb,
    const float* __restrict__ bias, float* __restrict__ out)
{
    __shared__ __align__(16) unsigned short smem[16384];   // 32 KB, 2 buffers

    const int t  = threadIdx.x;
    const int id = blockIdx.y * 12 + blockIdx.x;
    const int p8 = id & 7, j2 = id >> 3;
    const int bx = j2 % 12;
    const int by = p8 * 8 + j2 / 12;
    const int row0 = by * 64, col0 = bx * 64;

    const int lane = t & 63, wave = t >> 6;
    const int ln = lane & 15, quad = lane >> 4;
    const int lr  = lane >> 3;
    const int sc  = ((lane ^ lr) & 7) * 8;
    const int xsw = (ln & 7) << 3;

    const unsigned short* Ag = &Ab [(size_t)(row0 + wave*16 + lr) * Cdim + sc];
    const unsigned short* Bg = &wpb[(size_t)(col0 + wave*16 + lr) * Cdim + sc];

    float bv[4];
#pragma unroll
    for (int ni = 0; ni < 4; ++ni)
        bv[ni] = bias[col0 + ni*16 + ln];

    f32x4 acc[4] = {};

    // prologue: stage tile 0 into buffer 0
#pragma unroll
    for (int j = 0; j < 2; ++j) {
        gl_lds16(Ag + (size_t)(j*8) * Cdim, &smem[(wave*2 + j) * 512]);
        gl_lds16(Bg + (size_t)(j*8) * Cdim, &smem[4096 + (wave*2 + j) * 512]);
    }
    __syncthreads();

    int cur = 0;
    for (int k0 = 0; k0 < Cdim; k0 += 64) {
        unsigned short* bc = smem + cur * 8192;
        if (k0 + 64 < Cdim) {
            unsigned short* bn = smem + (cur ^ 1) * 8192;
            const int kn = k0 + 64;
#pragma unroll
            for (int j = 0; j < 2; ++j) {
                gl_lds16(Ag + (size_t)(j*8) * Cdim + kn, &bn[(wave*2 + j) * 512]);
                gl_lds16(Bg + (size_t)(j*8) * Cdim + kn, &bn[4096 + (wave*2 + j) * 512]);
            }
        }
#pragma unroll
        for (int kc = 0; kc < 2; ++kc) {
            short8 af = *(const short8*)&bc[(wave*16 + ln)*64
                                            + ((kc*32 + quad*8) ^ xsw)];
#pragma unroll
            for (int ni = 0; ni < 4; ++ni) {
                short8 bf = *(const short8*)&bc[4096 + (ni*16 + ln)*64
                                                + ((kc*32 + quad*8) ^ xsw)];
                acc[ni] = __builtin_amdgcn_mfma_f32_16x16x32_bf16(af, bf, acc[ni], 0, 0, 0);
            }
        }
        __syncthreads();
        cur ^= 1;
    }

    // epilogue: register-direct stores, fused bias (no LDS, no barriers).
    // Lanes 0..15 of each quad write 16 consecutive floats (64B segments).
#pragma unroll
    for (int ni = 0; ni < 4; ++ni)
#pragma unroll
        for (int reg = 0; reg < 4; ++reg)
            out[(size_t)(row0 + wave*16 + quad*4 + reg) * Cdim
                + col0 + ni*16 + ln] = acc[ni][reg] + bv[ni];
}

// ---------------------------------------------------------------------------
// Kernel 2: sliding-window attention, TQ=64 per block, 4 waves (frozen from
// r17). Wave w owns 16 query rows end-to-end; K[192][64] DMA-staged
// (clamped rows, masked post-MFMA); Vt granule-swizzled overlay; register
// softmax. LDS 51.4KB; grid 768, bijective XCD swizzle.
// ---------------------------------------------------------------------------
#define TQ2  64
#define VSTn 200
#define PSTn 200

__global__ __launch_bounds__(256) void swin_attn(
    const unsigned short* __restrict__ qkvb, unsigned short* __restrict__ ab)
{
    __shared__ __align__(16) unsigned short SH[64 * VSTn];   // 25600B K/Vt overlay
    __shared__ __align__(16) unsigned short Pl[TQ2][PSTn];   // 25600B
    __shared__ float psum[TQ2];                              //   256B

    const int t  = threadIdx.x;
    const int id = blockIdx.y * 32 + blockIdx.x;   // 768 blocks
    const int p8 = id & 7, j8 = id >> 3;           // 96 per XCD
    const int bh = j8 >> 2;
    const int i0 = (p8 * 4 + (j8 & 3)) * TQ2;
    const int b  = bh / Hh, h = bh % Hh;
    const int hoff = h * Dd;

    const int lane = t & 63, wave = t >> 6;
    const int ln = lane & 15, quad = lane >> 4;
    const int lr  = lane >> 3;
    const int scw = ((lane ^ lr) & 7) * 8;   // pre-swizzled src col (shorts)
    const int xsw = (ln & 7) << 3;           // read-side XOR
    const int rV  = t >> 3, c8 = t & 7;

    // ---- Q fragments (wave's 16 query rows)
    short8 qf[2];
#pragma unroll
    for (int kc = 0; kc < 2; ++kc)
        qf[kc] = *(const short8*)&qkvb[(size_t)(b * Nseq + i0 + wave*16 + ln) * E3
                                       + hoff + kc*32 + quad*8];

    // ---- V rows -> regs (clamped; P==0 exactly on masked/OOB keys)
    uint4 vreg[6];
#pragma unroll
    for (int j = 0; j < 6; ++j) {
        int g = i0 - HALF + rV + j*32;
        g = min(max(g, 0), Nseq - 1);
        vreg[j] = *(const uint4*)&qkvb[(size_t)(b * Nseq + g) * E3 + 2*Cdim + hoff + c8*8];
    }

    // ---- K -> LDS via DMA (24 x 8-row groups; clamped rows)
#pragma unroll
    for (int j = 0; j < 6; ++j) {
        const int base = (j*4 + wave) * 8;
        int g = i0 - HALF + base + lr;
        g = min(max(g, 0), Nseq - 1);
        gl_lds16(&qkvb[(size_t)(b * Nseq + g) * E3 + Cdim + hoff + scw],
                 &SH[base * 64]);
    }
    __syncthreads();

    // ---- S phase: wave's queries need key tiles [wave, wave+8]
    f32x4 sacc[9] = {};
#pragma unroll
    for (int kc = 0; kc < 2; ++kc)
#pragma unroll
        for (int tt = 0; tt < 9; ++tt) {
            short8 kf = *(const short8*)&SH[((wave + tt)*16 + ln)*64
                                            + ((kc*32 + quad*8) ^ xsw)];
            sacc[tt] = __builtin_amdgcn_mfma_f32_16x16x32_bf16(qf[kc], kf, sacc[tt], 0, 0, 0);
        }

    // ---- mask + row max, all register-local (wave owns full rows)
    float pm[4] = {-1e30f, -1e30f, -1e30f, -1e30f};
#pragma unroll
    for (int tt = 0; tt < 9; ++tt) {
        const int r = (wave + tt)*16 + ln;
        const int g = i0 - HALF + r;
#pragma unroll
        for (int reg = 0; reg < 4; ++reg) {
            const int q = wave*16 + quad*4 + reg;
            const bool valid = (r >= q) && (r <= q + 2*HALF) && (g >= 0) && (g < Nseq);
            const float s = valid ? sacc[tt][reg] * SCALEF : -1e30f;
            sacc[tt][reg] = s;
            pm[reg] = fmaxf(pm[reg], s);
        }
    }
#pragma unroll
    for (int reg = 0; reg < 4; ++reg) {
        pm[reg] = fmaxf(pm[reg], __shfl_xor(pm[reg], 1));
        pm[reg] = fmaxf(pm[reg], __shfl_xor(pm[reg], 2));
        pm[reg] = fmaxf(pm[reg], __shfl_xor(pm[reg], 4));
        pm[reg] = fmaxf(pm[reg], __shfl_xor(pm[reg], 8));
    }
    float ps[4] = {};
#pragma unroll
    for (int reg = 0; reg < 4; ++reg)
#pragma unroll
        for (int tt = 0; tt < 9; ++tt) {
            const float pv = (sacc[tt][reg] > -1e29f) ? __expf(sacc[tt][reg] - pm[reg]) : 0.f;
            sacc[tt][reg] = pv;
            ps[reg] += pv;
        }
#pragma unroll
    for (int reg = 0; reg < 4; ++reg) {
        ps[reg] += __shfl_xor(ps[reg], 1);
        ps[reg] += __shfl_xor(ps[reg], 2);
        ps[reg] += __shfl_xor(ps[reg], 4);
        ps[reg] += __shfl_xor(ps[reg], 8);
    }

    // ---- P stores, boundary-tile zero, psum store.
#pragma unroll
    for (int tt = 0; tt < 9; ++tt)
#pragma unroll
        for (int reg = 0; reg < 4; ++reg)
            Pl[wave*16 + quad*4 + reg][(wave + tt)*16 + ln] = f2bf(sacc[tt][reg]);
    {
        const int tz = (wave & 1) ? (wave - 1) : (wave + 9);
        *(uint2*)&Pl[wave*16 + ln][tz*16 + quad*4] = make_uint2(0u, 0u);
    }
    if (ln == 0)
#pragma unroll
        for (int reg = 0; reg < 4; ++reg)
            psum[wave*16 + quad*4 + reg] = ps[reg];
    __syncthreads();   // all waves' K reads complete -> Vt overlay safe

    // ---- Vt transpose stores, granule-swizzled (2-way banks = free)
#pragma unroll
    for (int j = 0; j < 6; ++j) {
        const int r = rV + j*32;
        const int gr = ((r >> 3) ^ c8)*8 + (r & 7);
        union { unsigned short us[8]; uint4 u; } pk; pk.u = vreg[j];
#pragma unroll
        for (int d8 = 0; d8 < 8; ++d8)
            SH[(c8*8 + d8)*VSTn + gr] = pk.us[d8];
    }
    __syncthreads();

    // ---- PV: wave's own 16 queries (cols), all 64 dims, 5 kc blocks
    const int kc0 = wave >> 1;
    f32x4 oacc[4] = {};
#pragma unroll
    for (int c = 0; c < 5; ++c) {
        const int kc = kc0 + c;
        short8 pf = *(const short8*)&Pl[wave*16 + ln][kc*32 + quad*8];
#pragma unroll
        for (int m = 0; m < 4; ++m) {
            const int d = m*16 + ln;
            short8 vf = *(const short8*)&SH[d * VSTn
                                            + (((kc*4 + quad) ^ (d >> 3)) << 3)];
            oacc[m] = __builtin_amdgcn_mfma_f32_16x16x32_bf16(vf, pf, oacc[m], 0, 0, 0);
        }
    }

    const int q = wave*16 + ln;
    const float inv = 1.f / psum[q];
    unsigned short* orow = &ab[(size_t)(b * Nseq + i0 + q) * Cdim + hoff];
#pragma unroll
    for (int m = 0; m < 4; ++m) {
        const int d0 = m*16 + quad*4;
        union { unsigned short us[4]; uint2 u2; } pk;
#pragma unroll
        for (int reg = 0; reg < 4; ++reg)
            pk.us[reg] = f2bf(oacc[m][reg] * inv);
        *(uint2*)&orow[d0] = pk.u2;
    }
}

// ---------------------------------------------------------------------------
extern "C" void kernel_launch(void* const* d_in, const int* in_sizes, int n_in,
                              void* d_out, int out_size, void* d_ws, size_t ws_size,
                              hipStream_t stream)
{
    const float* x      = (const float*)d_in[0];
    const float* w_qkv  = (const float*)d_in[1];
    const float* w_proj = (const float*)d_in[2];
    const float* b_proj = (const float*)d_in[3];
    float* out = (float*)d_out;

    unsigned short* qkvb = (unsigned short*)d_ws;   // 9,437,184 shorts
    unsigned short* ab   = qkvb + 9437184;          // 3,145,728 shorts
    unsigned short* xb   = ab   + 3145728;          // 3,145,728 shorts
    unsigned short* wqb  = xb   + 3145728;          // 1,769,472 shorts
    unsigned short* wpb  = wqb  + 1769472;          //   589,824 shorts (36.2MB total)

    cvt3<<<dim3(2688), 256, 0, stream>>>(x, w_qkv, w_proj, xb, wqb, wpb);
    qkv_mfma<<<dim3(18, 32), 256, 0, stream>>>(xb, wqb, qkvb);
    swin_attn<<<dim3(32, Bsz * Hh), 256, 0, stream>>>(qkvb, ab);
    proj_mfma<<<dim3(12, 64), 256, 0, stream>>>(ab, wpb, b_proj, out);
}